// Round 2
// baseline (212.139 us; speedup 1.0000x reference)
//
#include <hip/hip_runtime.h>
#include <hip/hip_bf16.h>

#define N_NODES 50000
#define N_EDGES 1600000
#define HEADS 8
#define HFD 16
#define CH 128      // channels

// bucketing: bucket = dst>>7 (128 dst nodes per bucket)
#define PART 128
#define NB 391              // ceil(50000/128)
#define BCAP 5120           // edge capacity per bucket (mean 4096, +16 sigma)
#define PA_T 512
#define PA_CHUNK 3200       // edges per pass-A block
#define PA_PER 7            // 512*7 = 3584 >= 3200
#define PA_BLOCKS 500       // 500*3200 = 1.6M

// k_aggr geometry: one block per EIGHTH bucket (16 dsts), 256 threads, 4 waves
#define OPART 16
#define ECAP 896            // per-eighth edge capacity (mean 512, +17 sigma)
#define AG_TASKS (NB * 8)   // 3128
#define AG_CHUNK 392
#define AG_BLOCKS 3136      // 8 * 392, multiple of 8 for XCD swizzle

#define RSTRIDE_B 288       // embr row: 128 bf16 emb (256 B) + 8 f32 left (32 B)

typedef __bf16 bf16x8 __attribute__((ext_vector_type(8)));
typedef __bf16 bf16x4 __attribute__((ext_vector_type(4)));
typedef float f32x4 __attribute__((ext_vector_type(4)));

__device__ __forceinline__ float bf_lo(unsigned u) { return __uint_as_float(u << 16); }
__device__ __forceinline__ float bf_hi(unsigned u) { return __uint_as_float(u & 0xffff0000u); }

// ---------------------------------------------------------------------------
// Prep kernel: split W f32 -> bf16 hi/lo; build 16x128 logit tile Veff and
// split it; zero bucket_cnt.
// ---------------------------------------------------------------------------
__global__ __launch_bounds__(256) void k_splitw(const float* __restrict__ W,
                                                const float* __restrict__ aL,
                                                const float* __restrict__ aR,
                                                __bf16* __restrict__ Whi,
                                                __bf16* __restrict__ Wlo,
                                                __bf16* __restrict__ Vhi,
                                                __bf16* __restrict__ Vlo,
                                                int* __restrict__ bucket_cnt) {
  int t = blockIdx.x * 256 + threadIdx.x;
  if (t < NB) bucket_cnt[t] = 0;
  if (t < CH * CH / 4) {
    f32x4 v = ((const f32x4*)W)[t];
    bf16x4 h, l;
#pragma unroll
    for (int i = 0; i < 4; ++i) {
      __bf16 hb = (__bf16)v[i];
      h[i] = hb;
      l[i] = (__bf16)(v[i] - (float)hb);
    }
    ((bf16x4*)Whi)[t] = h;
    ((bf16x4*)Wlo)[t] = l;
  }
  if (t < 16 * CH) {
    int j = t >> 7;          // 0..15: logit row (0..7 left, 8..15 right)
    int k = t & 127;         // input channel
    int h = j & 7;
    const float* a = (j < 8) ? aL : aR;
    float v = 0.f;
#pragma unroll
    for (int c = 0; c < HFD; ++c) v += W[(h * HFD + c) * CH + k] * a[c * HEADS + h];
    __bf16 hb = (__bf16)v;
    Vhi[t] = hb;
    Vlo[t] = (__bf16)(v - (float)hb);
  }
}

// ---------------------------------------------------------------------------
// emb = X @ W^T via split-bf16 MFMA. Writes 288 B rows: 128 bf16 emb channels
// + 8 f32 left-logits (so the aggregation gather gets left from the same
// cache lines as the emb row). right logits go to a separate dst-indexed arr.
// C/D: col=lane&15, row=(lane>>4)*4+r (HW-verified).
// ---------------------------------------------------------------------------
__global__ __launch_bounds__(64) void k_emb(const float* __restrict__ X,
                                            const __bf16* __restrict__ Whi,
                                            const __bf16* __restrict__ Wlo,
                                            const __bf16* __restrict__ Vhi,
                                            const __bf16* __restrict__ Vlo,
                                            unsigned char* __restrict__ embr,
                                            float* __restrict__ rightp) {
  int ntile = blockIdx.x;
  int lane = threadIdx.x;
  int c = lane & 15, quad = lane >> 4;
  const float* xp = X + (size_t)(ntile * 16 + c) * CH + quad * 8;
  bf16x8 xh[4], xl[4];
#pragma unroll
  for (int ks = 0; ks < 4; ++ks) {
    float4 x0 = *(const float4*)(xp + ks * 32);
    float4 x1 = *(const float4*)(xp + ks * 32 + 4);
    float xv[8] = {x0.x, x0.y, x0.z, x0.w, x1.x, x1.y, x1.z, x1.w};
#pragma unroll
    for (int j = 0; j < 8; ++j) {
      __bf16 hb = (__bf16)xv[j];
      xh[ks][j] = hb;
      xl[ks][j] = (__bf16)(xv[j] - (float)hb);
    }
  }
  // 8 head tiles -> bf16 emb
#pragma unroll
  for (int h = 0; h < HEADS; ++h) {
    const __bf16* wp = Whi + (size_t)(h * 16 + c) * CH + quad * 8;
    const __bf16* wlp = Wlo + (size_t)(h * 16 + c) * CH + quad * 8;
    f32x4 acc = {0.f, 0.f, 0.f, 0.f};
#pragma unroll
    for (int ks = 0; ks < 4; ++ks) {
      bf16x8 wh = *(const bf16x8*)(wp + ks * 32);
      bf16x8 wl = *(const bf16x8*)(wlp + ks * 32);
      acc = __builtin_amdgcn_mfma_f32_16x16x32_bf16(xl[ks], wh, acc, 0, 0, 0);
      acc = __builtin_amdgcn_mfma_f32_16x16x32_bf16(xh[ks], wl, acc, 0, 0, 0);
      acc = __builtin_amdgcn_mfma_f32_16x16x32_bf16(xh[ks], wh, acc, 0, 0, 0);
    }
#pragma unroll
    for (int r = 0; r < 4; ++r) {
      int node = ntile * 16 + quad * 4 + r;
      ((__bf16*)(embr + (size_t)node * RSTRIDE_B))[h * HFD + c] = (__bf16)acc[r];
    }
  }
  // logit tile: j<8 -> left head j (stored in-row as f32), j>=8 -> right
  {
    const __bf16* vp = Vhi + (size_t)c * CH + quad * 8;
    const __bf16* vlp = Vlo + (size_t)c * CH + quad * 8;
    f32x4 acc = {0.f, 0.f, 0.f, 0.f};
#pragma unroll
    for (int ks = 0; ks < 4; ++ks) {
      bf16x8 vh = *(const bf16x8*)(vp + ks * 32);
      bf16x8 vl = *(const bf16x8*)(vlp + ks * 32);
      acc = __builtin_amdgcn_mfma_f32_16x16x32_bf16(xl[ks], vh, acc, 0, 0, 0);
      acc = __builtin_amdgcn_mfma_f32_16x16x32_bf16(xh[ks], vl, acc, 0, 0, 0);
      acc = __builtin_amdgcn_mfma_f32_16x16x32_bf16(xh[ks], vh, acc, 0, 0, 0);
    }
#pragma unroll
    for (int r = 0; r < 4; ++r) {
      int node = ntile * 16 + quad * 4 + r;
      if (c < 8)
        *(float*)(embr + (size_t)node * RSTRIDE_B + 256 + c * 4) = acc[r];
      else
        rightp[node * HEADS + (c - 8)] = acc[r];
    }
  }
}

// ---------------------------------------------------------------------------
// Pass A: bucket edges by dst>>7. Packed 4 B edges held in REGISTERS through
// hist -> scan -> LDS bucket-sort, then run-contiguous global writes into
// per-bucket windows. p = (bucket:9 <<23) | (dstloc:7 <<16) | (src:16).
// ---------------------------------------------------------------------------
__global__ __launch_bounds__(PA_T) void k_bucket(const int* __restrict__ ei,
                                                 int* __restrict__ bucket_cnt,
                                                 unsigned* __restrict__ ebuf) {
  __shared__ unsigned sp[PA_CHUNK];   // 12.8 KB sorted edges
  __shared__ int hist[NB];
  __shared__ int lcur[NB];
  __shared__ int wbase[NB];
  __shared__ int scn[PA_T];
  int t = threadIdx.x;
  int base = blockIdx.x * PA_CHUNK;
  for (int i = t; i < NB; i += PA_T) hist[i] = 0;
  __syncthreads();
  unsigned pk[PA_PER];
#pragma unroll
  for (int i = 0; i < PA_PER; ++i) {
    int e = t + i * PA_T;
    pk[i] = 0xffffffffu;
    if (e < PA_CHUNK) {
      int src = ei[base + e];
      int dst = ei[N_EDGES + base + e];
      pk[i] = ((unsigned)(dst >> 7) << 23) | ((unsigned)(dst & 127) << 16) |
              (unsigned)src;
      atomicAdd(&hist[dst >> 7], 1);
    }
  }
  __syncthreads();
  // inclusive scan over NB buckets (padded Hillis-Steele over 512)
  scn[t] = (t < NB) ? hist[t] : 0;
  __syncthreads();
  int val = scn[t];
  for (int d = 1; d < PA_T; d <<= 1) {
    int o = (t >= d) ? scn[t - d] : 0;
    __syncthreads();
    val += o;
    scn[t] = val;
    __syncthreads();
  }
  if (t < NB) {
    int hv = hist[t];
    int lstart = val - hv;
    lcur[t] = lstart;
    int prior = hv ? atomicAdd(&bucket_cnt[t], hv) : 0;
    wbase[t] = t * BCAP + prior - lstart;
  }
  __syncthreads();
#pragma unroll
  for (int i = 0; i < PA_PER; ++i) {
    if (pk[i] != 0xffffffffu) {
      int b = pk[i] >> 23;
      int pos = atomicAdd(&lcur[b], 1);
      sp[pos] = pk[i];
    }
  }
  __syncthreads();
  for (int i = t; i < PA_CHUNK; i += PA_T) {
    unsigned p = sp[i];
    int b = p >> 23;
    int slot = wbase[b] + i;
    if (slot < (b + 1) * BCAP) ebuf[slot] = p;  // capacity guard (never fires)
  }
}

// ---------------------------------------------------------------------------
// Fused CSR-sort + pull-aggregate, v3. One block per EIGHTH-bucket (16 dsts,
// 256 threads, 3128 tasks -> 12.5K waves fills all 8K wave slots). Changes:
//  * FLATTENED per-wave edge stream: each wave owns 4 dsts; the depth-2
//    global pipeline runs continuously ACROSS dst boundaries (uniform flush
//    of the accumulator at each NEW-dst group) -> no per-dst pipeline drain.
//  * su indices prefetched one slot ahead of the global-issue slot, so the
//    LDS latency also pipelines.
//  * left logit now lives in the emb row (288 B rows) -> one gather stream.
//  * rightp for the block's 16 dsts preloaded to LDS (coalesced 512 B).
// ---------------------------------------------------------------------------
__global__ __launch_bounds__(256) void k_aggr(const int* __restrict__ bucket_cnt,
                                              const unsigned* __restrict__ ebuf,
                                              const unsigned char* __restrict__ embr,
                                              const float* __restrict__ rightp,
                                              const float* __restrict__ bias,
                                              float* __restrict__ out) {
  __shared__ unsigned short su[ECAP];   // 1.75 KB dstloc-sorted src ids
  __shared__ int hist[OPART];
  __shared__ int pfx[OPART];
  __shared__ int cur[OPART];
  __shared__ float r_lds[OPART * HEADS];
  // XCD-clustered task mapping: consecutive tasks share an XCD
  int T = (blockIdx.x & 7) * AG_CHUNK + (blockIdx.x >> 3);
  if (T >= AG_TASKS) return;
  int b = T >> 3;           // bucket
  int oct = T & 7;          // eighth within bucket (dstloc 16*oct..16*oct+15)
  int t = threadIdx.x;
  int blockbase = b * PART + oct * OPART;
  int cnt = bucket_cnt[b];
  if (cnt > BCAP) cnt = BCAP;
  int ebase = b * BCAP;
  if (t < OPART) hist[t] = 0;
  if (t < OPART * HEADS) {   // coalesced rightp preload (128 consecutive f32)
    int dst = blockbase + (t >> 3);
    r_lds[t] = (dst < N_NODES) ? rightp[dst * HEADS + (t & 7)] : 0.f;
  }
  __syncthreads();
  // pass 1: histogram this eighth's dstlocs (uint4 reads; tail over-read
  // stays inside the ebuf bucket window -> safe)
  for (int e4 = t * 4; e4 < cnt; e4 += 1024) {
    uint4 pp = *(const uint4*)(ebuf + ebase + e4);
    unsigned pj[4] = {pp.x, pp.y, pp.z, pp.w};
#pragma unroll
    for (int jj = 0; jj < 4; ++jj) {
      if (e4 + jj < cnt) {
        int dl = (pj[jj] >> 16) & 127;
        if ((dl >> 4) == oct) atomicAdd(&hist[dl & 15], 1);
      }
    }
  }
  __syncthreads();
  // 16-entry exclusive scan via wave-0 shuffles
  if (t < 64) {
    int v = (t < OPART) ? hist[t] : 0;
#pragma unroll
    for (int d = 1; d < OPART; d <<= 1) {
      int o = __shfl_up(v, d);
      if (t >= d) v += o;
    }
    if (t < OPART) {
      int ex = v - hist[t];
      pfx[t] = ex;
      cur[t] = ex;
    }
  }
  __syncthreads();
  // pass 2: scatter this eighth's srcs into su, sorted by dstloc
  for (int e4 = t * 4; e4 < cnt; e4 += 1024) {
    uint4 pp = *(const uint4*)(ebuf + ebase + e4);
    unsigned pj[4] = {pp.x, pp.y, pp.z, pp.w};
#pragma unroll
    for (int jj = 0; jj < 4; ++jj) {
      if (e4 + jj < cnt) {
        unsigned p = pj[jj];
        int dl = (p >> 16) & 127;
        if ((dl >> 4) == oct) {
          int pos = atomicAdd(&cur[dl & 15], 1);
          if (pos < ECAP) su[pos] = (unsigned short)(p & 0xffffu);
        }
      }
    }
  }
  __syncthreads();

  int wv = t >> 6;          // wave 0..3, each owns 4 dsts
  int lane = t & 63;
  int g = lane >> 4;        // edge group 0..3
  int m = lane & 15;        // 16 B slice: channels 8m..8m+7
  int h = m >> 1;           // head of this slice
  int wv4 = wv * 4;

  // clamped count of local dst jl (guards hypothetical su overflow)
  auto cdcf = [&](int jl) -> int {
    int p = pfx[jl], c = hist[jl], lim = ECAP - p;
    return c < lim ? c : lim;
  };

  int ng = 0;
#pragma unroll
  for (int j = 0; j < 4; ++j) {
    int c = cdcf(wv4 + j);
    if (c > 0) ng += (c + 7) >> 3;
  }

  float acc0 = 0.f, acc1 = 0.f, acc2 = 0.f, acc3 = 0.f;
  float acc4 = 0.f, acc5 = 0.f, acc6 = 0.f, acc7 = 0.f;
  float dsum = 0.f, r = 0.f;
  int jout = -1;

  // stage cursor
  int sj = 0, se = 0;
  while (sj < 4 && cdcf(wv4 + sj) <= 0) sj++;
  int ks = 0, gi = 0, kc = 0;

  int sA0 = 0, sA1 = 0, fA = 0, sB0 = 0, sB1 = 0, fB = 0;
  uint4 uA0, uA1, uB0, uB1;
  float lA0 = 0.f, lA1 = 0.f, lB0 = 0.f, lB1 = 0.f;
  int gfA = 0, gfB = 0;

  // SUF: fetch su pair + flags for the next group, advance cursor
#define SUF(S0v, S1v, Fv)                                                  \
  {                                                                        \
    int jl = wv4 + sj;                                                     \
    int beg = pfx[jl];                                                     \
    int cdc = cdcf(jl);                                                    \
    int i0 = se + g, i1 = se + 4 + g;                                      \
    int v0 = (i0 < cdc) ? 1 : 0, v1 = (i1 < cdc) ? 2 : 0;                  \
    S0v = su[beg + (v0 ? i0 : 0)];                                         \
    S1v = su[beg + (v1 ? i1 : 0)];                                         \
    Fv = v0 | v1 | ((se == 0) ? 4 : 0);                                    \
    se += 8;                                                               \
    if (se >= cdc) {                                                       \
      se = 0;                                                              \
      do { sj++; } while (sj < 4 && cdcf(wv4 + sj) <= 0);                  \
    }                                                                      \
    ks++;                                                                  \
  }

  // GLI: issue the global loads for a staged group
#define GLI(U0, U1, L0, L1, GF, S0v, S1v, Fv)                              \
  {                                                                        \
    unsigned ro0 = (unsigned)S0v * RSTRIDE_B;                              \
    unsigned ro1 = (unsigned)S1v * RSTRIDE_B;                              \
    U0 = *(const uint4*)(embr + ro0 + m * 16);                             \
    U1 = *(const uint4*)(embr + ro1 + m * 16);                             \
    L0 = *(const float*)(embr + ro0 + 256 + h * 4);                        \
    L1 = *(const float*)(embr + ro1 + 256 + h * 4);                        \
    GF = Fv;                                                               \
    gi++;                                                                  \
  }

#define FLUSH()                                                            \
  {                                                                        \
    float ds = dsum;                                                       \
    ds += __shfl_xor(ds, 16); ds += __shfl_xor(ds, 32);                    \
    float a0 = acc0 + __shfl_xor(acc0, 16);  a0 += __shfl_xor(a0, 32);     \
    float a1 = acc1 + __shfl_xor(acc1, 16);  a1 += __shfl_xor(a1, 32);     \
    float a2 = acc2 + __shfl_xor(acc2, 16);  a2 += __shfl_xor(a2, 32);     \
    float a3 = acc3 + __shfl_xor(acc3, 16);  a3 += __shfl_xor(a3, 32);     \
    float a4 = acc4 + __shfl_xor(acc4, 16);  a4 += __shfl_xor(a4, 32);     \
    float a5 = acc5 + __shfl_xor(acc5, 16);  a5 += __shfl_xor(a5, 32);     \
    float a6 = acc6 + __shfl_xor(acc6, 16);  a6 += __shfl_xor(a6, 32);     \
    float a7 = acc7 + __shfl_xor(acc7, 16);  a7 += __shfl_xor(a7, 32);     \
    int dsto = blockbase + wv4 + jout;                                     \
    if (g == 0 && dsto < N_NODES) {                                        \
      float inv = (ds > 0.f) ? 1.0f / ds : 0.f;                            \
      float4 b0 = ((const float4*)bias)[2 * m];                            \
      float4 b1 = ((const float4*)bias)[2 * m + 1];                        \
      float4 o0 = {a0 * inv + b0.x, a1 * inv + b0.y,                       \
                   a2 * inv + b0.z, a3 * inv + b0.w};                      \
      float4 o1 = {a4 * inv + b1.x, a5 * inv + b1.y,                       \
                   a6 * inv + b1.z, a7 * inv + b1.w};                      \
      ((float4*)(out + (size_t)dsto * CH))[2 * m] = o0;                    \
      ((float4*)(out + (size_t)dsto * CH))[2 * m + 1] = o1;                \
    }                                                                      \
  }

  // CON: consume a group (flush accumulator at dst boundary)
#define CON(U0, U1, L0, L1, GF)                                            \
  {                                                                        \
    if (GF & 4) {                                                          \
      if (jout >= 0) FLUSH();                                              \
      jout++;                                                              \
      while (jout < 3 && cdcf(wv4 + jout) <= 0) jout++;                    \
      r = r_lds[(wv4 + jout) * 8 + h];                                     \
      acc0 = acc1 = acc2 = acc3 = acc4 = acc5 = acc6 = acc7 = 0.f;         \
      dsum = 0.f;                                                          \
    }                                                                      \
    float x0 = L0 + r; x0 = (x0 >= 0.f) ? x0 : 0.2f * x0;                  \
    float w0 = (GF & 1) ? __expf(x0) : 0.f;                                \
    float x1 = L1 + r; x1 = (x1 >= 0.f) ? x1 : 0.2f * x1;                  \
    float w1 = (GF & 2) ? __expf(x1) : 0.f;                                \
    dsum += w0 + w1;                                                       \
    acc0 += w0 * bf_lo(U0.x) + w1 * bf_lo(U1.x);                           \
    acc1 += w0 * bf_hi(U0.x) + w1 * bf_hi(U1.x);                           \
    acc2 += w0 * bf_lo(U0.y) + w1 * bf_lo(U1.y);                           \
    acc3 += w0 * bf_hi(U0.y) + w1 * bf_hi(U1.y);                           \
    acc4 += w0 * bf_lo(U0.z) + w1 * bf_lo(U1.z);                           \
    acc5 += w0 * bf_hi(U0.z) + w1 * bf_hi(U1.z);                           \
    acc6 += w0 * bf_lo(U0.w) + w1 * bf_lo(U1.w);                           \
    acc7 += w0 * bf_hi(U0.w) + w1 * bf_hi(U1.w);                           \
    kc++;                                                                  \
  }

  if (ng > 0) {
    SUF(sA0, sA1, fA);
    if (ng > 1) SUF(sB0, sB1, fB);
    GLI(uA0, uA1, lA0, lA1, gfA, sA0, sA1, fA);
    while (true) {
      if (gi < ng) GLI(uB0, uB1, lB0, lB1, gfB, sB0, sB1, fB);
      if (ks < ng) SUF(sA0, sA1, fA);
      CON(uA0, uA1, lA0, lA1, gfA);
      if (kc >= ng) break;
      if (gi < ng) GLI(uA0, uA1, lA0, lA1, gfA, sA0, sA1, fA);
      if (ks < ng) SUF(sB0, sB1, fB);
      CON(uB0, uB1, lB0, lB1, gfB);
      if (kc >= ng) break;
    }
    FLUSH();
  }
#undef SUF
#undef GLI
#undef CON
#undef FLUSH

  // dsts with no edges: out = bias
#pragma unroll
  for (int j = 0; j < 4; ++j) {
    if (cdcf(wv4 + j) <= 0) {
      int dst = blockbase + wv4 + j;
      if (g == 0 && dst < N_NODES) {
        float4 b0 = ((const float4*)bias)[2 * m];
        float4 b1 = ((const float4*)bias)[2 * m + 1];
        ((float4*)(out + (size_t)dst * CH))[2 * m] = b0;
        ((float4*)(out + (size_t)dst * CH))[2 * m + 1] = b1;
      }
    }
  }
}

extern "C" void kernel_launch(void* const* d_in, const int* in_sizes, int n_in,
                              void* d_out, int out_size, void* d_ws, size_t ws_size,
                              hipStream_t stream) {
  const float* X = (const float*)d_in[0];
  const int* ei = (const int*)d_in[1];
  const float* W = (const float*)d_in[2];
  const float* al = (const float*)d_in[3];
  const float* ar = (const float*)d_in[4];
  const float* bias = (const float*)d_in[5];
  float* out = (float*)d_out;

  // workspace layout (~24.1 MB, same as before: leftp folded into embr rows)
  unsigned* ebuf = (unsigned*)d_ws;                          // NB*BCAP u32 (8.0 MB)
  unsigned char* embr = (unsigned char*)(ebuf + (size_t)NB * BCAP);  // N*288 B (14.4 MB)
  __bf16* Whi = (__bf16*)(embr + (size_t)N_NODES * RSTRIDE_B);  // 16K bf16
  __bf16* Wlo = Whi + CH * CH;                               // 16K bf16
  __bf16* Vhi = Wlo + CH * CH;                               // 2K bf16
  __bf16* Vlo = Vhi + 16 * CH;                               // 2K bf16
  float* rightp = (float*)(Vlo + 16 * CH);                   // N*8 f32
  int* bucket_cnt = (int*)(rightp + (size_t)N_NODES * HEADS);  // NB int

  k_splitw<<<16, 256, 0, stream>>>(W, al, ar, Whi, Wlo, Vhi, Vlo, bucket_cnt);
  k_bucket<<<PA_BLOCKS, PA_T, 0, stream>>>(ei, bucket_cnt, ebuf);
  k_emb<<<N_NODES / 16, 64, 0, stream>>>(X, Whi, Wlo, Vhi, Vlo, embr, rightp);
  k_aggr<<<AG_BLOCKS, 256, 0, stream>>>(bucket_cnt, ebuf, embr, rightp, bias, out);
}